// Round 1
// 202.148 us; speedup vs baseline: 1.0882x; 1.0882x over previous
//
#include <hip/hip_runtime.h>

// ---------------------------------------------------------------------------
// NUMERICS ARE FROZEN (R9 passed with absmax 0.0). hipcc defaults to
// -ffp-contract=fast, so this pragma is load-bearing: without it the seq-rn
// squares get FMA-fused and decisions flip (R1-R8 saga). Reference-exact
// decision function:
//   c2  = (cx*cx + cy*cy) + cz*cz            [seq rn]
//   p2  = (x*x + y*y) + z*z                  [seq rn]
//   dot = fmaf(cz,z, fmaf(cy,y, cx*x))       [ascending FMA chain]
//   d2  = (c2 + p2) - 2*dot                  [rn, rn]
//   hit = d2 < 0.01f                         [strict]
// R10 note: d2 is now fmaf(-2,dot,c2+p2). Bit-identical to (c2+p2)-2*dot:
// 2*dot is exact (pow2 scale, dot in [0,3)), so both forms round exactly
// once from the same exact value.
// ---------------------------------------------------------------------------
#pragma clang fp contract(off)

#define BQ_B 8
#define BQ_N 8192
#define BQ_M 2048
#define BQ_C 64
#define BQ_K 32
#define A_TILE 1024
#define A_WAVES 8
#define GB_M 1024

// ---------------------------------------------------------------------------
// Kernel A: index build. R10: the per-chunk `count < BQ_K` loop condition is
// hoisted to tile granularity so the 16-chunk scan can unroll (4x): ds_reads
// batch with offset immediates instead of serial read->use, loop control
// amortizes. Early exit loses almost nothing (expected hits ~34 vs K=32 ->
// 32nd hit lands at ~94% of the scan). Collector body verbatim from R6/R9;
// processing chunks after count>=K is a no-op (pos<K guard) and count
// overshoot is harmless (only compared against lane<K / pos<K).
// __launch_bounds__(512,8) pins VGPR<=64 so unroll can't cost occupancy
// (4 blocks/CU x 8 waves = 32 waves/CU).
// ---------------------------------------------------------------------------
__global__ __launch_bounds__(512, 8) void bq_index(
    const float* __restrict__ pts, const float* __restrict__ ctrs,
    int* __restrict__ idx_ws)
{
#pragma clang fp contract(off)
    __shared__ float4 tile[A_TILE];
    __shared__ int wlist[A_WAVES][BQ_K];

    const int tid  = threadIdx.x;
    const int lane = tid & 63;
    const int wave = tid >> 6;

    const int cid = blockIdx.x * A_WAVES + wave;  // 8 centers/block, same b
    const int b   = cid >> 11;
    const int m   = cid & (BQ_M - 1);

    const float cx = ctrs[(b * 3 + 0) * BQ_M + m];
    const float cy = ctrs[(b * 3 + 1) * BQ_M + m];
    const float cz = ctrs[(b * 3 + 2) * BQ_M + m];
    const float c2 = (cx * cx + cy * cy) + cz * cz;   // seq rn (frozen)

    const float* px = pts + (size_t)b * 3 * BQ_N;
    const float* py = px + BQ_N;
    const float* pz = py + BQ_N;

    int count = 0;
    for (int t0 = 0; t0 < BQ_N; t0 += A_TILE) {
        for (int i = tid; i < A_TILE; i += 512) {
            const int n = t0 + i;
            const float x = px[n];
            const float y = py[n];
            const float z = pz[n];
            const float p2 = (x * x + y * y) + z * z;  // seq rn (frozen)
            tile[i] = make_float4(x, y, z, p2);
        }
        __syncthreads();

        if (count < BQ_K) {                       // wave-uniform, tile-level
#pragma unroll 4
            for (int c0 = 0; c0 < A_TILE; c0 += 64) {
                const float4 p = tile[c0 + lane];
                const float dot = __builtin_fmaf(cz, p.z,
                                  __builtin_fmaf(cy, p.y, cx * p.x)); // frozen
                const float d2 = __builtin_fmaf(-2.0f, dot, c2 + p.w); // frozen (see header)
                const bool hit = d2 < 0.01f;                          // frozen
                const unsigned long long mask = __ballot(hit);
                if (mask) {
                    const int below =
                        (int)__popcll(mask & ((1ull << lane) - 1ull));
                    const int pos = count + below;
                    if (hit && pos < BQ_K) wlist[wave][pos] = t0 + c0 + lane;
                    count += (int)__popcll(mask);
                }
            }
        }
        __syncthreads();
    }

    int pad = 0;
    if (count > 0) pad = wlist[wave][0];
    if (lane >= count && lane < BQ_K) wlist[wave][lane] = pad;
    if (lane < BQ_K)
        idx_ws[(size_t)cid * BQ_K + lane] = wlist[wave][lane];
}

// ---------------------------------------------------------------------------
// Kernel B: gather, loop-inverted. R10: 512-thread blocks covering 1024 m
// each (grid 2x67x8). ctr staged only for this block's m-range: LDS
// 32 KB row + 4 KB ctr = 36 KB -> 4 blocks/CU x 8 waves = 32 waves/CU
// (was 16 with 256-thread/40 KB blocks). Row staging traffic halves
// (each (b,c) row staged 2x instead of 4x). Per-wave idx loads and float4
// stores remain contiguous 1 KB (lc = t>>3 spans 8 consecutive m per wave).
// Values bit-identical to R9: feature = raw copy, coord = single rn sub
// (contract off).
// ---------------------------------------------------------------------------
__global__ __launch_bounds__(512, 8) void bq_gather_row(
    const float* __restrict__ pts, const float* __restrict__ ctrs,
    const float* __restrict__ feats, const int* __restrict__ idx_ws,
    float* __restrict__ out)
{
#pragma clang fp contract(off)
    __shared__ float row[BQ_N];     // 32 KB
    __shared__ float ctr[GB_M];     // 4 KB (used only for c < 3)

    const int t  = threadIdx.x;
    const int c  = blockIdx.y;      // 0..66
    const int b  = blockIdx.z;      // 0..7
    const int m0 = blockIdx.x * GB_M;

    const float* src = (c < 3)
        ? pts   + (size_t)(b * 3 + c) * BQ_N
        : feats + (size_t)(b * BQ_C + (c - 3)) * BQ_N;

    for (int i = t; i < BQ_N / 4; i += 512)
        ((float4*)row)[i] = ((const float4*)src)[i];
    if (c < 3) {
        const float* csrc = ctrs + (b * 3 + c) * BQ_M + m0;
        for (int i = t; i < GB_M / 4; i += 512)
            ((float4*)ctr)[i] = ((const float4*)csrc)[i];
    }
    __syncthreads();

    const int lc = t >> 3;          // 0..63 local center
    const int k0 = (t & 7) * 4;     // k-group of 4

#pragma unroll 4
    for (int it = 0; it < GB_M / 64; ++it) {   // 16 iterations
        const int m = m0 + it * 64 + lc;
        const int4 iv =
            *(const int4*)(idx_ws + (size_t)(b * BQ_M + m) * BQ_K + k0);
        float4 v;
        v.x = row[iv.x];
        v.y = row[iv.y];
        v.z = row[iv.z];
        v.w = row[iv.w];
        if (c < 3) {
            const float cc = ctr[it * 64 + lc];
            v.x = v.x - cc;         // single rn sub (frozen, contract off)
            v.y = v.y - cc;
            v.z = v.z - cc;
            v.w = v.w - cc;
        }
        *(float4*)(out + ((size_t)((b * 67 + c) * BQ_M + m)) * BQ_K + k0) = v;
    }
}

extern "C" void kernel_launch(void* const* d_in, const int* in_sizes, int n_in,
                              void* d_out, int out_size, void* d_ws, size_t ws_size,
                              hipStream_t stream) {
    const float* pts   = (const float*)d_in[0];   // (B, 3, N)
    const float* ctrs  = (const float*)d_in[1];   // (B, 3, M)
    const float* feats = (const float*)d_in[2];   // (B, C, N)
    float* out = (float*)d_out;                   // (B, 67, M, K)
    int* idx = (int*)d_ws;                        // (B, M, K) ints = 2 MB
                                                  // (ws round-trip proven in
                                                  //  R1-R6 attribution runs)

    bq_index<<<dim3(BQ_B * BQ_M / A_WAVES), dim3(512), 0, stream>>>(
        pts, ctrs, idx);
    bq_gather_row<<<dim3(BQ_M / GB_M, 67, BQ_B), dim3(512), 0, stream>>>(
        pts, ctrs, feats, idx, out);
}

// Round 2
// 197.664 us; speedup vs baseline: 1.1129x; 1.0227x over previous
//
#include <hip/hip_runtime.h>

// ---------------------------------------------------------------------------
// NUMERICS ARE FROZEN (R9 passed with absmax 0.0). hipcc defaults to
// -ffp-contract=fast, so this pragma is load-bearing: without it the seq-rn
// squares get FMA-fused and decisions flip (R1-R8 saga). Reference-exact
// decision function:
//   c2  = (cx*cx + cy*cy) + cz*cz            [seq rn]
//   p2  = (x*x + y*y) + z*z                  [seq rn]
//   dot = fmaf(cz,z, fmaf(cy,y, cx*x))       [ascending FMA chain]
//   d2  = fmaf(-2, dot, c2 + p2)             [bit-identical to (c2+p2)-2*dot:
//                                             2*dot is an exact pow2 scale]
//   hit = d2 < 0.01f                         [strict]
// ---------------------------------------------------------------------------
#pragma clang fp contract(off)

#define BQ_B 8
#define BQ_N 8192
#define BQ_M 2048
#define BQ_C 64
#define BQ_K 32
#define A_TILE 1024
#define A_WAVES 8
#define A_CPW 4          // centers per wave (R11: amortize ds_read_b128 4x)
#define GB_M 1024

// ---------------------------------------------------------------------------
// Kernel A: index build. R11 theory: R10 was LDS-read-bound, not VALU-bound —
// 8 waves/block each re-read the whole tile (2.1M ds_read_b128 total = ~41 us
// of LDS pipe at 12 cyc each), vs ~12 us of decision VALU. Fix: each wave now
// owns A_CPW=4 centers, so one ds_read_b128 feeds 4 centers' worth of VALU.
// Total VALU work is invariant in C; LDS traffic drops 4x (~10 us/CU).
// 512 blocks x 8 waves = 4 waves/SIMD; per-chunk VALU (~48 cyc) x 4 waves
// covers the ~120 cyc ds_read latency; unroll 2 adds ILP margin.
// Early-exit widened to "all 4 centers full" — worth ~6% at best (expected
// hits ~34 vs K=32; ~half the centers are boundary-clipped and scan fully),
// so the weaker condition loses nothing. Collector body verbatim per center;
// count overshoot harmless (pos<K / lane<K guards).
// ---------------------------------------------------------------------------
__global__ __launch_bounds__(512, 8) void bq_index(
    const float* __restrict__ pts, const float* __restrict__ ctrs,
    int* __restrict__ idx_ws)
{
#pragma clang fp contract(off)
    __shared__ float4 tile[A_TILE];
    __shared__ int wlist[A_WAVES][A_CPW][BQ_K];

    const int tid  = threadIdx.x;
    const int lane = tid & 63;
    const int wave = tid >> 6;

    // 32 consecutive centers per block, same b (64 blocks per batch exactly)
    const int cid0 = (blockIdx.x * A_WAVES + wave) * A_CPW;
    const int b    = cid0 >> 11;
    const int m0   = cid0 & (BQ_M - 1);

    float cx[A_CPW], cy[A_CPW], cz[A_CPW], c2[A_CPW];
    int count[A_CPW];
#pragma unroll
    for (int j = 0; j < A_CPW; ++j) {
        const int m = m0 + j;
        cx[j] = ctrs[(b * 3 + 0) * BQ_M + m];
        cy[j] = ctrs[(b * 3 + 1) * BQ_M + m];
        cz[j] = ctrs[(b * 3 + 2) * BQ_M + m];
        c2[j] = (cx[j] * cx[j] + cy[j] * cy[j]) + cz[j] * cz[j]; // seq rn
        count[j] = 0;
    }

    const float* px = pts + (size_t)b * 3 * BQ_N;
    const float* py = px + BQ_N;
    const float* pz = py + BQ_N;

    for (int t0 = 0; t0 < BQ_N; t0 += A_TILE) {
        for (int i = tid; i < A_TILE; i += 512) {
            const int n = t0 + i;
            const float x = px[n];
            const float y = py[n];
            const float z = pz[n];
            const float p2 = (x * x + y * y) + z * z;  // seq rn (frozen)
            tile[i] = make_float4(x, y, z, p2);
        }
        __syncthreads();

        if (count[0] < BQ_K || count[1] < BQ_K ||
            count[2] < BQ_K || count[3] < BQ_K) {      // wave-uniform
#pragma unroll 2
            for (int c0 = 0; c0 < A_TILE; c0 += 64) {
                const float4 p = tile[c0 + lane];
#pragma unroll
                for (int j = 0; j < A_CPW; ++j) {
                    const float dot = __builtin_fmaf(cz[j], p.z,
                                      __builtin_fmaf(cy[j], p.y,
                                                     cx[j] * p.x)); // frozen
                    const float d2 =
                        __builtin_fmaf(-2.0f, dot, c2[j] + p.w);    // frozen
                    const bool hit = d2 < 0.01f;                    // frozen
                    const unsigned long long mask = __ballot(hit);
                    if (mask) {
                        const int below =
                            (int)__popcll(mask & ((1ull << lane) - 1ull));
                        const int pos = count[j] + below;
                        if (hit && pos < BQ_K)
                            wlist[wave][j][pos] = t0 + c0 + lane;
                        count[j] += (int)__popcll(mask);
                    }
                }
            }
        }
        __syncthreads();
    }

#pragma unroll
    for (int j = 0; j < A_CPW; ++j) {
        int pad = 0;
        if (count[j] > 0) pad = wlist[wave][j][0];
        if (lane >= count[j] && lane < BQ_K) wlist[wave][j][lane] = pad;
        if (lane < BQ_K)
            idx_ws[(size_t)(cid0 + j) * BQ_K + lane] = wlist[wave][j][lane];
    }
}

// ---------------------------------------------------------------------------
// Kernel B: gather, loop-inverted (unchanged from R10 — within ~10% of its
// write-dominated roofline: 140.5 MB out + ~50 MB reads @ 6.7 TB/s ~ 28 us).
// 512-thread blocks covering 1024 m each; LDS 36 KB -> 4 blocks/CU x 8 waves
// = 32 waves/CU. Values bit-identical: feature = raw copy, coord = single rn
// sub (contract off).
// ---------------------------------------------------------------------------
__global__ __launch_bounds__(512, 8) void bq_gather_row(
    const float* __restrict__ pts, const float* __restrict__ ctrs,
    const float* __restrict__ feats, const int* __restrict__ idx_ws,
    float* __restrict__ out)
{
#pragma clang fp contract(off)
    __shared__ float row[BQ_N];     // 32 KB
    __shared__ float ctr[GB_M];     // 4 KB (used only for c < 3)

    const int t  = threadIdx.x;
    const int c  = blockIdx.y;      // 0..66
    const int b  = blockIdx.z;      // 0..7
    const int m0 = blockIdx.x * GB_M;

    const float* src = (c < 3)
        ? pts   + (size_t)(b * 3 + c) * BQ_N
        : feats + (size_t)(b * BQ_C + (c - 3)) * BQ_N;

    for (int i = t; i < BQ_N / 4; i += 512)
        ((float4*)row)[i] = ((const float4*)src)[i];
    if (c < 3) {
        const float* csrc = ctrs + (b * 3 + c) * BQ_M + m0;
        for (int i = t; i < GB_M / 4; i += 512)
            ((float4*)ctr)[i] = ((const float4*)csrc)[i];
    }
    __syncthreads();

    const int lc = t >> 3;          // 0..63 local center
    const int k0 = (t & 7) * 4;     // k-group of 4

#pragma unroll 4
    for (int it = 0; it < GB_M / 64; ++it) {   // 16 iterations
        const int m = m0 + it * 64 + lc;
        const int4 iv =
            *(const int4*)(idx_ws + (size_t)(b * BQ_M + m) * BQ_K + k0);
        float4 v;
        v.x = row[iv.x];
        v.y = row[iv.y];
        v.z = row[iv.z];
        v.w = row[iv.w];
        if (c < 3) {
            const float cc = ctr[it * 64 + lc];
            v.x = v.x - cc;         // single rn sub (frozen, contract off)
            v.y = v.y - cc;
            v.z = v.z - cc;
            v.w = v.w - cc;
        }
        *(float4*)(out + ((size_t)((b * 67 + c) * BQ_M + m)) * BQ_K + k0) = v;
    }
}

extern "C" void kernel_launch(void* const* d_in, const int* in_sizes, int n_in,
                              void* d_out, int out_size, void* d_ws, size_t ws_size,
                              hipStream_t stream) {
    const float* pts   = (const float*)d_in[0];   // (B, 3, N)
    const float* ctrs  = (const float*)d_in[1];   // (B, 3, M)
    const float* feats = (const float*)d_in[2];   // (B, C, N)
    float* out = (float*)d_out;                   // (B, 67, M, K)
    int* idx = (int*)d_ws;                        // (B, M, K) ints = 2 MB
                                                  // (ws round-trip proven in
                                                  //  R1-R6 attribution runs)

    bq_index<<<dim3(BQ_B * BQ_M / (A_WAVES * A_CPW)), dim3(512), 0, stream>>>(
        pts, ctrs, idx);
    bq_gather_row<<<dim3(BQ_M / GB_M, 67, BQ_B), dim3(512), 0, stream>>>(
        pts, ctrs, feats, idx, out);
}